// Round 3
// baseline (67.511 us; speedup 1.0000x reference)
//
#include <hip/hip_runtime.h>
#include <stdint.h>

#define B 8
#define H 192
#define W 192
#define NPIX (B * H * W) /* 294912 */
#define NROWS (B * H)    /* 1536 */
#define NCOL (B * W)     /* 1536 */
#define INFF 1e12f

#define SLOTS 2                        /* rows in flight per block */
#define ITERS 2                        /* serial row iterations */
#define ROWS_PB (SLOTS * ITERS)        /* 4 rows per block */
#define NTHR (SLOTS * W)               /* 384 threads = 6 waves */
#define KBLK (NROWS / ROWS_PB)         /* 384 blocks */

// ---------------------------------------------------------------------------
// Nearest set bit (clamped to 255) from position h in a 192-bit column bitset
// (s2:s1:s0), inclusive of h. Proven exact (absmax 0 across sessions).
// ---------------------------------------------------------------------------
__device__ __forceinline__ int hi_pos(uint64_t w0, uint64_t w1, uint64_t w2) {
  if (w2) return 191 - __builtin_clzll(w2);
  if (w1) return 127 - __builtin_clzll(w1);
  if (w0) return 63 - __builtin_clzll(w0);
  return -255;  // none below -> distance >= 255
}
__device__ __forceinline__ int lo_pos(uint64_t w0, uint64_t w1, uint64_t w2) {
  if (w0) return __builtin_ctzll(w0);
  if (w1) return 64 + __builtin_ctzll(w1);
  if (w2) return 128 + __builtin_ctzll(w2);
  return 447;  // none above -> distance >= 255
}
__device__ __forceinline__ int nearest_dist(uint64_t s0, uint64_t s1,
                                            uint64_t s2, int h) {
  int k = h >> 6, r = h & 63;
  uint64_t keepL = (2ull << r) - 1;  // bits 0..r (r=63 -> all ones)
  uint64_t b0 = s0, b1 = s1, b2 = s2;
  if (k == 0) { b0 &= keepL; b1 = 0; b2 = 0; }
  else if (k == 1) { b1 &= keepL; b2 = 0; }
  else { b2 &= keepL; }
  int dbelow = h - hi_pos(b0, b1, b2);
  uint64_t keepU = (~0ull) << r;  // bits r..63
  uint64_t a0 = s0, a1 = s1, a2 = s2;
  if (k == 0) { a0 &= keepU; }
  else if (k == 1) { a0 = 0; a1 &= keepU; }
  else { a0 = 0; a1 = 0; a2 &= keepU; }
  int dabove = lo_pos(a0, a1, a2) - h;
  return min(min(dbelow, dabove), 255);
}

// ---------------------------------------------------------------------------
// K1: column bitmask build — VERBATIM from the 64.9 us baseline (one block
// per (b,w) column, 3 wave64 ballots, lane-0 stores, SoA masks layout), plus
// one thread zeroing out[0] so K2 can atomically accumulate into it (the
// kernel boundary provides release/acquire visibility — no fences).
// R1/R2 lesson: fusing this into the row pass forces a per-block whole-image
// rebuild that costs more than the dispatch it saves. Keep the global
// 72 KB mask exchange.
// ---------------------------------------------------------------------------
__global__ __launch_bounds__(192) void col_mask(
    const float* __restrict__ pred, const float* __restrict__ targ,
    uint64_t* __restrict__ masks, float* __restrict__ out) {
  int bw = blockIdx.x;  // 0..NCOL
  int b = bw / W, w = bw % W;
  int h = threadIdx.x;
  int idx = b * H * W + h * W + w;
  uint64_t bp = __ballot(pred[idx] > 0.0f);  // sigmoid(x)>0.5 <=> x>0
  uint64_t bt = __ballot(targ[idx] > 0.5f);
  if ((h & 63) == 0) {
    int wv = h >> 6;
    masks[wv * NCOL + bw] = bp;
    masks[(3 + wv) * NCOL + bw] = bt;
  }
  if (bw == 0 && h == 0) out[0] = 0.0f;  // accumulator init for K2
}

// ---------------------------------------------------------------------------
// K2': row pass + fused final reduce. 384 blocks x 384 threads; each block
// owns 4 consecutive rows of one batch (2 slots x 2 iterations; slot
// boundaries wave-aligned since 64 | 192). Per-thread: 6 coalesced mask-word
// loads ONCE (reused across both iterations), then the proven row body:
// packed 4xu8 column distances, LDS exchange, early-exit horizontal scan,
// fused sigmoid/error/ratio, per-row 64-lane shuffle + 3-word tree (order
// bit-identical to baseline). Block then folds its 4 row sums in fixed
// order and issues ONE fp32 atomicAdd of bsum/NPIX to out[0].
// 384 same-address atomics, staggered by block completion ≈ 1-2 us — vs
// ~5-7 us for the reduce_pass launch+drain it replaces. No __threadfence
// (R6 lesson: device-scope fences cost ~20 ns x count on 8 XCDs).
// NOTE: cross-row accumulation order is now atomic-arrival order -> absmax
// expected ~1e-7 relative instead of 0.0 (within harness tolerance).
// ---------------------------------------------------------------------------
__global__ __launch_bounds__(NTHR) void row_pass(
    const float* __restrict__ pred, const float* __restrict__ targ,
    const uint64_t* __restrict__ masks, float* __restrict__ out) {
  int blk = blockIdx.x;
  int bh0 = blk * ROWS_PB;
  int b = bh0 / H, h0 = bh0 - b * H;  // 4 | 192: block never straddles batches
  int t = threadIdx.x;
  int slot = t / W, w = t - slot * W;

  __shared__ uint32_t sm[SLOTS][W];
  __shared__ float wsum[SLOTS][3];
  __shared__ float rsum[ROWS_PB];

  int cw = b * W + w;
  uint64_t p0 = masks[0 * NCOL + cw], p1 = masks[1 * NCOL + cw],
           p2 = masks[2 * NCOL + cw];
  uint64_t q0 = masks[3 * NCOL + cw], q1 = masks[4 * NCOL + cw],
           q2 = masks[5 * NCOL + cw];

  for (int it = 0; it < ITERS; ++it) {
    int h = h0 + it * SLOTS + slot;
    int base = b * H * W + h * W;
    float xv = pred[base + w];  // coalesced per 192-thread row group
    float tv = targ[base + w];

    int k = h >> 6, rb = h & 63;
    uint64_t pw = (k == 0) ? p0 : ((k == 1) ? p1 : p2);
    uint64_t qw = (k == 0) ? q0 : ((k == 1) ? q1 : q2);
    int mp = (int)((pw >> rb) & 1);  // == (xv > 0)
    int mt = (int)((qw >> rb) & 1);  // == (tv > 0.5)
    int sp = nearest_dist(mp ? ~p0 : p0, mp ? ~p1 : p1, mp ? ~p2 : p2, h);
    int st = nearest_dist(mt ? ~q0 : q0, mt ? ~q1 : q1, mt ? ~q2 : q2, h);
    int dFp = mp ? sp : 0, dTp = mp ? 0 : sp;
    int dFt = mt ? st : 0, dTt = mt ? 0 : st;
    uint32_t own = (uint32_t)dFp | ((uint32_t)dTp << 8) |
                   ((uint32_t)dFt << 16) | ((uint32_t)dTt << 24);
    sm[slot][w] = own;
    __syncthreads();  // S1: sm(it) visible

    int shp = (xv > 0.0f) ? 0 : 8;   // fg pixel needs fg-EDT field, else bg
    int sht = (tv > 0.5f) ? 16 : 24;
    int dp = (own >> shp) & 255;
    int dt = (own >> sht) & 255;
    float bp = (dp == 255) ? INFF : (float)(dp * dp);
    float bt = (dt == 255) ? INFF : (float)(dt * dt);
    for (int r = 1; r < W; ++r) {
      float rr = (float)(r * r);
      if (rr >= fmaxf(bp, bt)) break;  // farther q can't improve either min
      int ql = w - r, qr = w + r;
      if (ql >= 0) {
        uint32_t v = sm[slot][ql];
        int a = (v >> shp) & 255, c = (v >> sht) & 255;
        bp = fminf(bp, (a == 255) ? INFF : rr + (float)(a * a));
        bt = fminf(bt, (c == 255) ? INFF : rr + (float)(c * c));
      }
      if (qr < W) {
        uint32_t v = sm[slot][qr];
        int a = (v >> shp) & 255, c = (v >> sht) & 255;
        bp = fminf(bp, (a == 255) ? INFF : rr + (float)(a * a));
        bt = fminf(bt, (c == 255) ? INFF : rr + (float)(c * c));
      }
    }

    float p = 1.0f / (1.0f + __expf(-xv));
    float e = p - tv;
    float err = e * e;
    float pd = sqrtf(bp), td = sqrtf(bt);
    float s = pd + td;
    float term = err * (bp + bt) / (s * s);  // bp,bt >= 1 always: no 0/0

    // per-row reduction, tree bit-identical to the 64.9 us baseline
    for (int off = 32; off > 0; off >>= 1) term += __shfl_down(term, off, 64);
    if ((w & 63) == 0) wsum[slot][w >> 6] = term;
    __syncthreads();  // S2: scan reads of sm(it) done; wsum(it) visible
    if (w == 0)
      rsum[it * SLOTS + slot] = wsum[slot][0] + wsum[slot][1] + wsum[slot][2];
    // next iteration's sm/wsum writes are safe: every thread passed S2, so
    // all scan reads of sm(it) and wsum reads completed. rsum(it) is only
    // read after S3 below.
  }
  __syncthreads();  // S3: rsum visible
  if (t == 0) {
    float bsum = (rsum[0] + rsum[1]) + (rsum[2] + rsum[3]);
    atomicAdd(out, bsum * (1.0f / (float)NPIX));
  }
}

extern "C" void kernel_launch(void* const* d_in, const int* in_sizes, int n_in,
                              void* d_out, int out_size, void* d_ws,
                              size_t ws_size, hipStream_t stream) {
  const float* pred = (const float*)d_in[0];
  const float* targ = (const float*)d_in[1];
  float* out = (float*)d_out;
  uint64_t* masks = (uint64_t*)d_ws;  // 6*NCOL u64 = 72 KB

  col_mask<<<NCOL, 192, 0, stream>>>(pred, targ, masks, out);
  row_pass<<<KBLK, NTHR, 0, stream>>>(pred, targ, masks, out);
}

// Round 4
// 64.853 us; speedup vs baseline: 1.0410x; 1.0410x over previous
//
#include <hip/hip_runtime.h>
#include <stdint.h>

#define B 8
#define H 192
#define W 192
#define NPIX (B * H * W) /* 294912 */
#define NROWS (B * H)    /* 1536 */
#define NCOL (B * W)     /* 1536 */
#define INFF 1e12f

// ---------------------------------------------------------------------------
// Nearest set bit (clamped to 255) from position h in a 192-bit column bitset
// (s2:s1:s0), inclusive of h. Proven exact (absmax 0 across sessions).
// ---------------------------------------------------------------------------
__device__ __forceinline__ int hi_pos(uint64_t w0, uint64_t w1, uint64_t w2) {
  if (w2) return 191 - __builtin_clzll(w2);
  if (w1) return 127 - __builtin_clzll(w1);
  if (w0) return 63 - __builtin_clzll(w0);
  return -255;  // none below -> distance >= 255
}
__device__ __forceinline__ int lo_pos(uint64_t w0, uint64_t w1, uint64_t w2) {
  if (w0) return __builtin_ctzll(w0);
  if (w1) return 64 + __builtin_ctzll(w1);
  if (w2) return 128 + __builtin_ctzll(w2);
  return 447;  // none above -> distance >= 255
}
__device__ __forceinline__ int nearest_dist(uint64_t s0, uint64_t s1,
                                            uint64_t s2, int h) {
  int k = h >> 6, r = h & 63;
  uint64_t keepL = (2ull << r) - 1;  // bits 0..r (r=63 -> all ones)
  uint64_t b0 = s0, b1 = s1, b2 = s2;
  if (k == 0) { b0 &= keepL; b1 = 0; b2 = 0; }
  else if (k == 1) { b1 &= keepL; b2 = 0; }
  else { b2 &= keepL; }
  int dbelow = h - hi_pos(b0, b1, b2);
  uint64_t keepU = (~0ull) << r;  // bits r..63
  uint64_t a0 = s0, a1 = s1, a2 = s2;
  if (k == 0) { a0 &= keepU; }
  else if (k == 1) { a0 = 0; a1 &= keepU; }
  else { a0 = 0; a1 = 0; a2 &= keepU; }
  int dabove = lo_pos(a0, a1, a2) - h;
  return min(min(dbelow, dabove), 255);
}

// ---------------------------------------------------------------------------
// K1 v2: COALESCED column-bitmask build via ballot + LDS bit-transpose.
// Old version: block per column, lane = h -> stride-768B loads, every
// wave-load touched 64 cache lines (37 MB L2 traffic for 2.4 MB of input).
// New: block = (batch b, 64-column group wg, 64-row word k); 256 threads.
//  Phase 1: lane = column -> fully coalesced 256B wave-loads. Each wave
//   owns 16 rows; loads staged into registers 16-deep (blocks are ~1/CU,
//   so ILP, not TLP, hides latency), then __ballot gives the ROW mask
//   (bit l = pixel(row, col wg*64+l)), lane 0 stores to LDS.
//  Phase 2: threads 0..127 (src = t/64, col-lane l = t%64) assemble the
//   COLUMN word: bit j = rowmask[j] >> l. LDS reads are wave-uniform
//   (broadcast, conflict-free). Output bits/layout identical to the old
//   ballot-per-column kernel -> downstream bit-identical (absmax 0).
// R1/R2 lesson kept: masks go through global (72 KB), no rebuild per block.
// R6 lesson kept: no fences/atomics anywhere.
// ---------------------------------------------------------------------------
__global__ __launch_bounds__(256) void col_mask(
    const float* __restrict__ pred, const float* __restrict__ targ,
    uint64_t* __restrict__ masks) {
  int blk = blockIdx.x;          // 0..71
  int b = blk / 9;
  int rem = blk - b * 9;
  int wg = rem / 3, k = rem - wg * 3;  // column group, row-word index
  int t = threadIdx.x;
  int lane = t & 63, wv = t >> 6;  // 4 waves, 16 rows each

  __shared__ uint64_t rmp[64];  // row masks, pred
  __shared__ uint64_t rmt[64];  // row masks, targ

  {
    int j0 = wv * 16;
    int base = b * H * W + (k * 64 + j0) * W + wg * 64 + lane;
    float pv[16], tv[16];
#pragma unroll
    for (int jj = 0; jj < 16; ++jj) {
      pv[jj] = pred[base + jj * W];  // coalesced: lane = consecutive column
      tv[jj] = targ[base + jj * W];
    }
#pragma unroll
    for (int jj = 0; jj < 16; ++jj) {
      uint64_t bp = __ballot(pv[jj] > 0.0f);  // sigmoid(x)>0.5 <=> x>0
      uint64_t bt = __ballot(tv[jj] > 0.5f);
      if (lane == 0) {
        rmp[j0 + jj] = bp;
        rmt[j0 + jj] = bt;
      }
    }
  }
  __syncthreads();

  if (t < 128) {
    const uint64_t* rm = (t >= 64) ? rmt : rmp;
    uint64_t wrd = 0;
#pragma unroll
    for (int j = 0; j < 64; ++j) wrd |= ((rm[j] >> lane) & 1ull) << j;
    int word_row = ((t >= 64) ? 3 : 0) + k;  // SoA: 0..2 pred, 3..5 targ
    masks[word_row * NCOL + b * W + wg * 64 + lane] = wrd;
  }
}

// ---------------------------------------------------------------------------
// K2: row pass + fused loss — VERBATIM from the 64.9 us baseline. One block
// per (b, h) row, one thread per w. Thread w loads column w's 6 mask words
// (coalesced), derives its pixel's packed 4 x u8 column distances with TWO
// nearest-opposite bit scans, shares via LDS, then the proven early-exit
// horizontal scan (exact). Fused sigmoid/error/ratio; one partial store per
// block (no atomics — R3 measured same-address atomic tail ~6 ns/op).
// ---------------------------------------------------------------------------
__global__ __launch_bounds__(192) void row_pass(
    const float* __restrict__ pred, const float* __restrict__ targ,
    const uint64_t* __restrict__ masks, float* __restrict__ partial) {
  int bh = blockIdx.x;
  int b = bh / H, h = bh % H;
  int w = threadIdx.x;
  __shared__ uint32_t sm[W];
  __shared__ float wsum[3];
  int cw = b * W + w;
  uint64_t p0 = masks[0 * NCOL + cw], p1 = masks[1 * NCOL + cw],
           p2 = masks[2 * NCOL + cw];
  uint64_t q0 = masks[3 * NCOL + cw], q1 = masks[4 * NCOL + cw],
           q2 = masks[5 * NCOL + cw];
  int base = b * H * W + h * W;
  float xv = pred[base + w];
  float tv = targ[base + w];

  int k = h >> 6, rb = h & 63;
  uint64_t pw = (k == 0) ? p0 : ((k == 1) ? p1 : p2);
  uint64_t qw = (k == 0) ? q0 : ((k == 1) ? q1 : q2);
  int mp = (int)((pw >> rb) & 1);  // == (xv > 0)
  int mt = (int)((qw >> rb) & 1);  // == (tv > 0.5)
  int sp = nearest_dist(mp ? ~p0 : p0, mp ? ~p1 : p1, mp ? ~p2 : p2, h);
  int st = nearest_dist(mt ? ~q0 : q0, mt ? ~q1 : q1, mt ? ~q2 : q2, h);
  int dFp = mp ? sp : 0, dTp = mp ? 0 : sp;
  int dFt = mt ? st : 0, dTt = mt ? 0 : st;
  uint32_t own = (uint32_t)dFp | ((uint32_t)dTp << 8) | ((uint32_t)dFt << 16) |
                 ((uint32_t)dTt << 24);
  sm[w] = own;
  __syncthreads();

  int shp = (xv > 0.0f) ? 0 : 8;   // fg pixel needs fg-EDT field, else bg
  int sht = (tv > 0.5f) ? 16 : 24;
  int dp = (own >> shp) & 255;
  int dt = (own >> sht) & 255;
  float bp = (dp == 255) ? INFF : (float)(dp * dp);
  float bt = (dt == 255) ? INFF : (float)(dt * dt);
  for (int r = 1; r < W; ++r) {
    float rr = (float)(r * r);
    if (rr >= fmaxf(bp, bt)) break;  // farther q can't improve either min
    int ql = w - r, qr = w + r;
    if (ql >= 0) {
      uint32_t v = sm[ql];
      int a = (v >> shp) & 255, c = (v >> sht) & 255;
      bp = fminf(bp, (a == 255) ? INFF : rr + (float)(a * a));
      bt = fminf(bt, (c == 255) ? INFF : rr + (float)(c * c));
    }
    if (qr < W) {
      uint32_t v = sm[qr];
      int a = (v >> shp) & 255, c = (v >> sht) & 255;
      bp = fminf(bp, (a == 255) ? INFF : rr + (float)(a * a));
      bt = fminf(bt, (c == 255) ? INFF : rr + (float)(c * c));
    }
  }

  float p = 1.0f / (1.0f + __expf(-xv));
  float e = p - tv;
  float err = e * e;
  float pd = sqrtf(bp), td = sqrtf(bt);
  float s = pd + td;
  float term = err * (bp + bt) / (s * s);  // bp,bt >= 1 always: no 0/0

  for (int off = 32; off > 0; off >>= 1) term += __shfl_down(term, off, 64);
  if ((w & 63) == 0) wsum[w >> 6] = term;
  __syncthreads();
  if (w == 0) partial[bh] = wsum[0] + wsum[1] + wsum[2];
}

// ---------------------------------------------------------------------------
// K3: final reduce of 1536 row partials -> mean — VERBATIM from baseline.
// Plain store to d_out (overwrites harness poison; no atomics, no fences).
// ---------------------------------------------------------------------------
__global__ __launch_bounds__(256) void reduce_pass(
    const float* __restrict__ partial, float* __restrict__ out) {
  int t = threadIdx.x;
  float s = 0.0f;
#pragma unroll
  for (int i = t; i < NROWS; i += 256) s += partial[i];
  for (int off = 32; off > 0; off >>= 1) s += __shfl_down(s, off, 64);
  __shared__ float ws[4];
  if ((t & 63) == 0) ws[t >> 6] = s;
  __syncthreads();
  if (t == 0) out[0] = (ws[0] + ws[1] + ws[2] + ws[3]) * (1.0f / (float)NPIX);
}

extern "C" void kernel_launch(void* const* d_in, const int* in_sizes, int n_in,
                              void* d_out, int out_size, void* d_ws,
                              size_t ws_size, hipStream_t stream) {
  const float* pred = (const float*)d_in[0];
  const float* targ = (const float*)d_in[1];
  float* out = (float*)d_out;
  uint64_t* masks = (uint64_t*)d_ws;                              // 6*NCOL u64
  float* partial = (float*)((char*)d_ws + (size_t)6 * NCOL * 8);  // NROWS f32

  col_mask<<<B * 3 * 3, 256, 0, stream>>>(pred, targ, masks);
  row_pass<<<NROWS, 192, 0, stream>>>(pred, targ, masks, partial);
  reduce_pass<<<1, 256, 0, stream>>>(partial, out);
}